// Round 2
// baseline (469.148 us; speedup 1.0000x reference)
//
#include <hip/hip_runtime.h>

#define SEQ   4096
#define CDIM  256
#define NHEAD 4
#define DHEAD 64

typedef float    f32x4 __attribute__((ext_vector_type(4)));
typedef _Float16 f16x8 __attribute__((ext_vector_type(8)));

// load 8 contiguous fp32, convert to fp16x8 fragment
__device__ __forceinline__ f16x8 cvt_frag(const float* __restrict__ p) {
    float4 f0 = *(const float4*)p;
    float4 f1 = *(const float4*)(p + 4);
    f16x8 r;
    r[0]=(_Float16)f0.x; r[1]=(_Float16)f0.y; r[2]=(_Float16)f0.z; r[3]=(_Float16)f0.w;
    r[4]=(_Float16)f1.x; r[5]=(_Float16)f1.y; r[6]=(_Float16)f1.z; r[7]=(_Float16)f1.w;
    return r;
}

// ---------------- Kernel 1: fused QKV projection ----------------
// out = x @ w.T + b for q,k,v.  Q stored [b][h][n][d] pre-scaled by 1/16 (fp16),
// K stored [b][h][n][d] (fp16), V stored transposed [b][h][d][n] (fp16).
__global__ __launch_bounds__(256) void sta_qkv(
    const float* __restrict__ x,
    const float* __restrict__ qw, const float* __restrict__ qb,
    const float* __restrict__ kw, const float* __restrict__ kb,
    const float* __restrict__ vw, const float* __restrict__ vb,
    _Float16* __restrict__ Qo, _Float16* __restrict__ Ko, _Float16* __restrict__ Vo)
{
    const int wave = threadIdx.x >> 6;
    const int lane = threadIdx.x & 63;
    const int l15  = lane & 15;
    const int quad = lane >> 4;
    const int row0 = blockIdx.x * 64 + wave * 16;

    // A fragments: x rows, m = lane&15, k = quad*8 + j  (verified gfx950 layout)
    f16x8 af[8];
    const float* xrow = x + (row0 + l15) * CDIM + quad * 8;
    #pragma unroll
    for (int ks = 0; ks < 8; ks++) af[ks] = cvt_frag(xrow + ks * 32);

    #pragma unroll 1
    for (int mat = 0; mat < 3; mat++) {
        const float* w    = (mat == 0) ? qw : (mat == 1) ? kw : vw;
        const float* bias = (mat == 0) ? qb : (mat == 1) ? kb : vb;
        #pragma unroll 1
        for (int ct = 0; ct < 16; ct++) {
            const int c = ct * 16 + l15;                  // output channel (B col, n=lane&15)
            const float* wr = w + c * CDIM + quad * 8;    // B[k][n] = w[n][k], contiguous in k
            f32x4 acc = {0.f, 0.f, 0.f, 0.f};
            #pragma unroll
            for (int ks = 0; ks < 8; ks++) {
                f16x8 bf = cvt_frag(wr + ks * 32);
                acc = __builtin_amdgcn_mfma_f32_16x16x32_f16(af[ks], bf, acc, 0, 0, 0);
            }
            const float bv = bias[c];
            const int h = c >> 6, d = c & 63;
            #pragma unroll
            for (int r = 0; r < 4; r++) {
                // C/D layout: col = lane&15, row = quad*4 + r
                const int grow = row0 + quad * 4 + r;
                const int b = grow >> 12;          // /4096
                const int n = grow & (SEQ - 1);
                float val = acc[r] + bv;
                if (mat == 0) {
                    Qo[((b * NHEAD + h) * SEQ + n) * DHEAD + d] = (_Float16)(val * 0.0625f);
                } else if (mat == 1) {
                    Ko[((b * NHEAD + h) * SEQ + n) * DHEAD + d] = (_Float16)val;
                } else {
                    Vo[((b * NHEAD + h) * DHEAD + d) * SEQ + n] = (_Float16)val;
                }
            }
        }
    }
}

// ---------------- Kernel 2: flash attention with soft-threshold gate ----------------
// grid = 8 (b*h) * 64 (q-tiles of 64).  4 waves/block, wave owns 16 Q rows.
__global__ __launch_bounds__(256) void sta_attn(
    const _Float16* __restrict__ Q, const _Float16* __restrict__ K, const _Float16* __restrict__ Vt,
    const float* __restrict__ taup,
    _Float16* __restrict__ AO)   // attn out, fp16 [b][n][c]
{
    __shared__ __align__(16) _Float16 lds[4][16 * 72];   // per-wave P relayout buffer (stride 72)

    const int wave = threadIdx.x >> 6;
    const int lane = threadIdx.x & 63;
    const int l15  = lane & 15;
    const int quad = lane >> 4;
    const int bh = blockIdx.x >> 6;     // 0..7
    const int qt = blockIdx.x & 63;
    const int b = bh >> 2, h = bh & 3;
    const float tau_eff = fmaxf(taup[0], 0.0f);   // relu(where(|a|>tau,a,0)) == a*(a>max(tau,0))

    const _Float16* Qb = Q  + bh * SEQ * DHEAD;
    const _Float16* Kb = K  + bh * SEQ * DHEAD;
    const _Float16* Vb = Vt + bh * DHEAD * SEQ;

    const int row0 = qt * 64 + wave * 16;

    // Q A-fragments (Q already scaled by 1/16)
    f16x8 qf0 = *(const f16x8*)(Qb + (row0 + l15) * DHEAD + quad * 8);
    f16x8 qf1 = *(const f16x8*)(Qb + (row0 + l15) * DHEAD + 32 + quad * 8);

    f32x4 O[4];
    #pragma unroll
    for (int ct = 0; ct < 4; ct++) O[ct] = (f32x4){0.f, 0.f, 0.f, 0.f};
    float m_[4] = {0.f, 0.f, 0.f, 0.f};    // gated logits are >= 0, so 0 is a safe init max
    float l_[4] = {0.f, 0.f, 0.f, 0.f};

    _Float16* myl = lds[wave];

    #pragma unroll 1
    for (int kt = 0; kt < 64; kt++) {
        const int kv0 = kt * 64;

        // ---- S = Q K^T (already includes 1/16 scale via Q) ----
        f32x4 s[4];
        #pragma unroll
        for (int ct = 0; ct < 4; ct++) {
            const _Float16* kp = Kb + (kv0 + ct * 16 + l15) * DHEAD + quad * 8;
            f16x8 b0 = *(const f16x8*)kp;
            f16x8 b1 = *(const f16x8*)(kp + 32);
            f32x4 a = {0.f, 0.f, 0.f, 0.f};
            a = __builtin_amdgcn_mfma_f32_16x16x32_f16(qf0, b0, a, 0, 0, 0);
            a = __builtin_amdgcn_mfma_f32_16x16x32_f16(qf1, b1, a, 0, 0, 0);
            s[ct] = a;
        }

        // ---- gate + row max (rows live in quad: row = quad*4 + r, cols across 16 lanes) ----
        float rm[4];
        #pragma unroll
        for (int r = 0; r < 4; r++) {
            float mx = 0.f;
            #pragma unroll
            for (int ct = 0; ct < 4; ct++) {
                float gv = (s[ct][r] > tau_eff) ? s[ct][r] : 0.f;
                s[ct][r] = gv;
                mx = fmaxf(mx, gv);
            }
            mx = fmaxf(mx, __shfl_xor(mx, 1));
            mx = fmaxf(mx, __shfl_xor(mx, 2));
            mx = fmaxf(mx, __shfl_xor(mx, 4));
            mx = fmaxf(mx, __shfl_xor(mx, 8));
            rm[r] = mx;
        }

        float alpha[4];
        #pragma unroll
        for (int r = 0; r < 4; r++) {
            float mn = fmaxf(m_[r], rm[r]);
            alpha[r] = __expf(m_[r] - mn);
            m_[r] = mn;
        }

        // ---- p = exp(s - m), row sum (zeros contribute exp(-m)) ----
        float rs[4] = {0.f, 0.f, 0.f, 0.f};
        #pragma unroll
        for (int ct = 0; ct < 4; ct++) {
            #pragma unroll
            for (int r = 0; r < 4; r++) {
                float p = __expf(s[ct][r] - m_[r]);
                s[ct][r] = p;
                rs[r] += p;
            }
        }
        #pragma unroll
        for (int r = 0; r < 4; r++) {
            float v = rs[r];
            v += __shfl_xor(v, 1);
            v += __shfl_xor(v, 2);
            v += __shfl_xor(v, 4);
            v += __shfl_xor(v, 8);
            l_[r] = l_[r] * alpha[r] + v;
        }

        // ---- rescale O, write P to LDS (C/D layout -> [row][col], stride 72) ----
        #pragma unroll
        for (int ct = 0; ct < 4; ct++) {
            #pragma unroll
            for (int r = 0; r < 4; r++) {
                O[ct][r] *= alpha[r];
                myl[(quad * 4 + r) * 72 + ct * 16 + l15] = (_Float16)s[ct][r];
            }
        }

        // ---- read P back as A-operand fragments (same-wave LDS; compiler waits lgkmcnt) ----
        f16x8 pa0 = *(const f16x8*)(myl + l15 * 72 + quad * 8);
        f16x8 pa1 = *(const f16x8*)(myl + l15 * 72 + 32 + quad * 8);

        // ---- O += P V  (Vt rows are head-dim, contiguous in kv) ----
        #pragma unroll
        for (int ct = 0; ct < 4; ct++) {
            const _Float16* vp = Vb + (ct * 16 + l15) * SEQ + kv0 + quad * 8;
            f16x8 v0 = *(const f16x8*)vp;
            f16x8 v1 = *(const f16x8*)(vp + 32);
            O[ct] = __builtin_amdgcn_mfma_f32_16x16x32_f16(pa0, v0, O[ct], 0, 0, 0);
            O[ct] = __builtin_amdgcn_mfma_f32_16x16x32_f16(pa1, v1, O[ct], 0, 0, 0);
        }
    }

    // ---- epilogue: normalize, store fp16 attn_out [b][n][c] ----
    #pragma unroll
    for (int ct = 0; ct < 4; ct++) {
        const int c = h * 64 + ct * 16 + l15;
        #pragma unroll
        for (int r = 0; r < 4; r++) {
            const int n = row0 + quad * 4 + r;
            float val = O[ct][r] / l_[r];
            AO[(b * SEQ + n) * CDIM + c] = (_Float16)val;
        }
    }
}

// ---------------- Kernel 3: output projection ----------------
__global__ __launch_bounds__(256) void sta_oproj(
    const _Float16* __restrict__ AO,
    const float* __restrict__ ow, const float* __restrict__ ob,
    float* __restrict__ out)
{
    const int wave = threadIdx.x >> 6;
    const int lane = threadIdx.x & 63;
    const int l15  = lane & 15;
    const int quad = lane >> 4;
    const int row0 = blockIdx.x * 64 + wave * 16;

    f16x8 af[8];
    const _Float16* arow = AO + (row0 + l15) * CDIM + quad * 8;
    #pragma unroll
    for (int ks = 0; ks < 8; ks++) af[ks] = *(const f16x8*)(arow + ks * 32);

    #pragma unroll 1
    for (int ct = 0; ct < 16; ct++) {
        const int c = ct * 16 + l15;
        const float* wr = ow + c * CDIM + quad * 8;
        f32x4 acc = {0.f, 0.f, 0.f, 0.f};
        #pragma unroll
        for (int ks = 0; ks < 8; ks++) {
            f16x8 bf = cvt_frag(wr + ks * 32);
            acc = __builtin_amdgcn_mfma_f32_16x16x32_f16(af[ks], bf, acc, 0, 0, 0);
        }
        const float bv = ob[c];
        #pragma unroll
        for (int r = 0; r < 4; r++) {
            out[(row0 + quad * 4 + r) * CDIM + c] = acc[r] + bv;
        }
    }
}

extern "C" void kernel_launch(void* const* d_in, const int* in_sizes, int n_in,
                              void* d_out, int out_size, void* d_ws, size_t ws_size,
                              hipStream_t stream) {
    const float* x   = (const float*)d_in[0];
    const float* qw  = (const float*)d_in[1];
    const float* qb  = (const float*)d_in[2];
    const float* kw  = (const float*)d_in[3];
    const float* kb  = (const float*)d_in[4];
    const float* vw  = (const float*)d_in[5];
    const float* vb  = (const float*)d_in[6];
    const float* ow  = (const float*)d_in[7];
    const float* ob  = (const float*)d_in[8];
    const float* tau = (const float*)d_in[9];

    // workspace layout (fp16): Q | K | Vt | AO, each 2*4*4096*64 = 2097152 elems (4 MB)
    _Float16* ws = (_Float16*)d_ws;
    _Float16* Q  = ws;
    _Float16* Kb = ws + 2097152;
    _Float16* Vt = ws + 4194304;
    _Float16* AO = ws + 6291456;

    sta_qkv <<<128, 256, 0, stream>>>(x, qw, qb, kw, kb, vw, vb, Q, Kb, Vt);
    sta_attn<<<512, 256, 0, stream>>>(Q, Kb, Vt, tau, AO);
    sta_oproj<<<128, 256, 0, stream>>>(AO, ow, ob, (float*)d_out);
}

// Round 3
// 377.909 us; speedup vs baseline: 1.2414x; 1.2414x over previous
//
#include <hip/hip_runtime.h>

#define SEQ   4096
#define CDIM  256
#define NHEAD 4
#define DHEAD 64
#define LSTRIDE 68   // LDS row stride (elems): 8B-aligned rows, quads spread over banks {0,8,16,24}

typedef float    f32x4 __attribute__((ext_vector_type(4)));
typedef _Float16 f16x8 __attribute__((ext_vector_type(8)));
typedef _Float16 f16x4 __attribute__((ext_vector_type(4)));

__device__ __forceinline__ f16x8 cvt_frag(const float* __restrict__ p) {
    float4 f0 = *(const float4*)p;
    float4 f1 = *(const float4*)(p + 4);
    f16x8 r;
    r[0]=(_Float16)f0.x; r[1]=(_Float16)f0.y; r[2]=(_Float16)f0.z; r[3]=(_Float16)f0.w;
    r[4]=(_Float16)f1.x; r[5]=(_Float16)f1.y; r[6]=(_Float16)f1.z; r[7]=(_Float16)f1.w;
    return r;
}

// ---------------- Kernel 0: weight fp32->fp16 prep ----------------
// w16 layout: [qw | kw | vw | ow], each 256*256 fp16, same [c][k] order as source.
__global__ __launch_bounds__(256) void sta_prep(
    const float* __restrict__ qw, const float* __restrict__ kw,
    const float* __restrict__ vw, const float* __restrict__ ow,
    _Float16* __restrict__ w16)
{
    const int mat = blockIdx.y;
    const float* src = (mat == 0) ? qw : (mat == 1) ? kw : (mat == 2) ? vw : ow;
    const int i = (blockIdx.x * 256 + threadIdx.x) * 8;   // 32 blocks * 256 thr * 8 = 65536
    *(f16x8*)(w16 + mat * 65536 + i) = cvt_frag(src + i);
}

// ---------------- Kernel 1: QKV projection ----------------
// grid (128 row-tiles, 3 mats, 2 channel-halves), 256 thr.
// Q: [bh][n][d] *1/16; K: [bh][n][d]; V: transposed [bh][d][n]. All fp16.
__global__ __launch_bounds__(256) void sta_qkv(
    const float* __restrict__ x, const _Float16* __restrict__ w16,
    const float* __restrict__ qb, const float* __restrict__ kb, const float* __restrict__ vb,
    _Float16* __restrict__ Qo, _Float16* __restrict__ Ko, _Float16* __restrict__ Vo)
{
    const int wave = threadIdx.x >> 6;
    const int lane = threadIdx.x & 63;
    const int l15  = lane & 15;
    const int quad = lane >> 4;
    const int mat  = blockIdx.y;
    const int half = blockIdx.z;
    const int row0 = blockIdx.x * 64 + wave * 16;

    const _Float16* w    = w16 + mat * 65536;
    const float*    bias = (mat == 0) ? qb : (mat == 1) ? kb : vb;

    // x fragments (dual-use as A or B operand: lane=row/col=l15, k=quad*8+j contiguous)
    f16x8 xf[8];
    const float* xrow = x + (row0 + l15) * CDIM + quad * 8;
    #pragma unroll
    for (int ks = 0; ks < 8; ks++) xf[ks] = cvt_frag(xrow + ks * 32);

    #pragma unroll 1
    for (int ct = 0; ct < 8; ct++) {
        const int ctg = half * 8 + ct;
        const _Float16* wr = w + (ctg * 16 + l15) * CDIM + quad * 8;
        f32x4 acc = {0.f, 0.f, 0.f, 0.f};
        if (mat < 2) {
            // C = W x^T : row = channel (quad*4+r), col = token (l15) -> packed d-store
            #pragma unroll
            for (int ks = 0; ks < 8; ks++)
                acc = __builtin_amdgcn_mfma_f32_16x16x32_f16(*(const f16x8*)(wr + ks * 32), xf[ks], acc, 0, 0, 0);
            const float4 bv = *(const float4*)(bias + ctg * 16 + quad * 4);
            const int c0 = ctg * 16 + quad * 4;
            const int h = c0 >> 6, d0 = c0 & 63;
            const int grow = row0 + l15, b = grow >> 12, n = grow & (SEQ - 1);
            const float sc = (mat == 0) ? 0.0625f : 1.0f;
            f16x4 o;
            o[0] = (_Float16)((acc[0] + bv.x) * sc);
            o[1] = (_Float16)((acc[1] + bv.y) * sc);
            o[2] = (_Float16)((acc[2] + bv.z) * sc);
            o[3] = (_Float16)((acc[3] + bv.w) * sc);
            _Float16* dst = ((mat == 0) ? Qo : Ko) + (((b * NHEAD + h) * SEQ + n) * DHEAD + d0);
            *(f16x4*)dst = o;
        } else {
            // C = x W^T : row = token (quad*4+r), col = channel (l15) -> packed n-store into Vt
            #pragma unroll
            for (int ks = 0; ks < 8; ks++)
                acc = __builtin_amdgcn_mfma_f32_16x16x32_f16(xf[ks], *(const f16x8*)(wr + ks * 32), acc, 0, 0, 0);
            const int c = ctg * 16 + l15;
            const int h = c >> 6, d = c & 63;
            const float bv = bias[c];
            const int grow0 = row0 + quad * 4, b = grow0 >> 12, n0 = grow0 & (SEQ - 1);
            f16x4 o;
            #pragma unroll
            for (int r = 0; r < 4; r++) o[r] = (_Float16)(acc[r] + bv);
            *(f16x4*)(Vo + (((b * NHEAD + h) * DHEAD + d) * SEQ + n0)) = o;
        }
    }
}

// ---------------- Kernel 2: flash attention, split-KV, no online max ----------------
// grid (128 q-tiles of 32, 8 bh, 4 kv-splits), 128 thr (2 waves, 16 q-rows each).
__global__ __launch_bounds__(128) void sta_attn(
    const _Float16* __restrict__ Q, const _Float16* __restrict__ K, const _Float16* __restrict__ Vt,
    const float* __restrict__ taup,
    float* __restrict__ Opart, float* __restrict__ lpart)
{
    __shared__ __align__(16) _Float16 lds[2][2][16 * LSTRIDE];  // [wave][kt&1]

    const int wave = threadIdx.x >> 6;
    const int lane = threadIdx.x & 63;
    const int l15  = lane & 15;
    const int quad = lane >> 4;
    const int bh = blockIdx.y;
    const int sp = blockIdx.z;
    const float tau_eff = fmaxf(taup[0], 0.0f);

    const _Float16* Qb = Q  + bh * SEQ * DHEAD;
    const _Float16* Kb = K  + bh * SEQ * DHEAD;
    const _Float16* Vb = Vt + bh * DHEAD * SEQ;

    const int row0 = blockIdx.x * 32 + wave * 16;

    const f16x8 qf0 = *(const f16x8*)(Qb + (row0 + l15) * DHEAD + quad * 8);
    const f16x8 qf1 = *(const f16x8*)(Qb + (row0 + l15) * DHEAD + 32 + quad * 8);

    f32x4 O[4];
    #pragma unroll
    for (int ct = 0; ct < 4; ct++) O[ct] = (f32x4){0.f, 0.f, 0.f, 0.f};
    f32x4 rs = {0.f, 0.f, 0.f, 0.f};   // per-lane row-sum partials (row = quad*4+r)

    #pragma unroll 2
    for (int kt = sp * 16; kt < sp * 16 + 16; kt++) {
        const int kv0 = kt * 64;
        _Float16* buf = lds[wave][kt & 1];

        // ---- S = Q K^T (1/16 scale folded into Q). No max subtraction needed:
        // logits bounded ~|4|, exp fits fp32 with huge margin.
        f32x4 s[4];
        #pragma unroll
        for (int ct = 0; ct < 4; ct++) {
            const _Float16* kp = Kb + (kv0 + ct * 16 + l15) * DHEAD + quad * 8;
            f16x8 b0 = *(const f16x8*)kp;
            f16x8 b1 = *(const f16x8*)(kp + 32);
            f32x4 a = {0.f, 0.f, 0.f, 0.f};
            a = __builtin_amdgcn_mfma_f32_16x16x32_f16(qf0, b0, a, 0, 0, 0);
            a = __builtin_amdgcn_mfma_f32_16x16x32_f16(qf1, b1, a, 0, 0, 0);
            s[ct] = a;
        }

        // ---- p = gated exp (gate-off -> exp(0)=1), accumulate per-lane row sums,
        //      write P to LDS in [qrow][kvcol] for the A-operand relayout.
        #pragma unroll
        for (int ct = 0; ct < 4; ct++) {
            #pragma unroll
            for (int r = 0; r < 4; r++) {
                float e = __expf(s[ct][r]);
                float p = (s[ct][r] > tau_eff) ? e : 1.0f;
                rs[r] += p;
                buf[(quad * 4 + r) * LSTRIDE + ct * 16 + l15] = (_Float16)p;
            }
        }

        // ---- P A-fragments (b64-aligned reads at stride 68) ----
        f16x4 p00 = *(const f16x4*)(buf + l15 * LSTRIDE + quad * 8);
        f16x4 p01 = *(const f16x4*)(buf + l15 * LSTRIDE + quad * 8 + 4);
        f16x4 p10 = *(const f16x4*)(buf + l15 * LSTRIDE + 32 + quad * 8);
        f16x4 p11 = *(const f16x4*)(buf + l15 * LSTRIDE + 32 + quad * 8 + 4);
        f16x8 pa0, pa1;
        #pragma unroll
        for (int j = 0; j < 4; j++) { pa0[j] = p00[j]; pa0[j+4] = p01[j]; pa1[j] = p10[j]; pa1[j+4] = p11[j]; }

        // ---- O += P V ----
        #pragma unroll
        for (int ct = 0; ct < 4; ct++) {
            const _Float16* vp = Vb + (ct * 16 + l15) * SEQ + kv0 + quad * 8;
            f16x8 v0 = *(const f16x8*)vp;
            f16x8 v1 = *(const f16x8*)(vp + 32);
            O[ct] = __builtin_amdgcn_mfma_f32_16x16x32_f16(pa0, v0, O[ct], 0, 0, 0);
            O[ct] = __builtin_amdgcn_mfma_f32_16x16x32_f16(pa1, v1, O[ct], 0, 0, 0);
        }
    }

    // ---- epilogue: one 16-lane reduction for l, store fp32 partials ----
    #pragma unroll
    for (int r = 0; r < 4; r++) {
        float v = rs[r];
        v += __shfl_xor(v, 1);
        v += __shfl_xor(v, 2);
        v += __shfl_xor(v, 4);
        v += __shfl_xor(v, 8);
        rs[r] = v;
    }
    float* Ob = Opart + (size_t)((sp * 8 + bh) * SEQ + row0) * DHEAD;
    #pragma unroll
    for (int ct = 0; ct < 4; ct++)
        #pragma unroll
        for (int r = 0; r < 4; r++)
            Ob[(quad * 4 + r) * DHEAD + ct * 16 + l15] = O[ct][r];
    if (l15 == 0) {
        #pragma unroll
        for (int r = 0; r < 4; r++)
            lpart[(sp * 8 + bh) * SEQ + row0 + quad * 4 + r] = rs[r];
    }
}

// ---------------- Kernel 3: combine split-KV partials ----------------
__global__ __launch_bounds__(256) void sta_combine(
    const float* __restrict__ Opart, const float* __restrict__ lpart,
    _Float16* __restrict__ AO)
{
    const int idx = blockIdx.x * 256 + threadIdx.x;     // 524288
    const int dg = idx & 15, n = (idx >> 4) & (SEQ - 1), bh = idx >> 16;
    const int d0 = dg * 4;
    float4 o = {0.f, 0.f, 0.f, 0.f};
    float l = 0.f;
    #pragma unroll
    for (int s = 0; s < 4; s++) {
        const float4 os = *(const float4*)(Opart + (size_t)((s * 8 + bh) * SEQ + n) * DHEAD + d0);
        o.x += os.x; o.y += os.y; o.z += os.z; o.w += os.w;
        l += lpart[(s * 8 + bh) * SEQ + n];
    }
    const float inv = 1.0f / l;
    const int b = bh >> 2, h = bh & 3;
    f16x4 res;
    res[0] = (_Float16)(o.x * inv); res[1] = (_Float16)(o.y * inv);
    res[2] = (_Float16)(o.z * inv); res[3] = (_Float16)(o.w * inv);
    *(f16x4*)(AO + (size_t)(b * SEQ + n) * CDIM + h * DHEAD + d0) = res;
}

// ---------------- Kernel 4: output projection ----------------
// grid (128 row-tiles, 4 channel-quarters), 256 thr.  C = W ao^T -> float4 stores.
__global__ __launch_bounds__(256) void sta_oproj(
    const _Float16* __restrict__ AO, const _Float16* __restrict__ w16o,
    const float* __restrict__ ob, float* __restrict__ out)
{
    const int wave = threadIdx.x >> 6;
    const int lane = threadIdx.x & 63;
    const int l15  = lane & 15;
    const int quad = lane >> 4;
    const int row0 = blockIdx.x * 64 + wave * 16;
    const int quarter = blockIdx.y;

    f16x8 af[8];
    const _Float16* arow = AO + (row0 + l15) * CDIM + quad * 8;
    #pragma unroll
    for (int ks = 0; ks < 8; ks++) af[ks] = *(const f16x8*)(arow + ks * 32);

    #pragma unroll 1
    for (int ct = 0; ct < 4; ct++) {
        const int ctg = quarter * 4 + ct;
        const _Float16* wr = w16o + (ctg * 16 + l15) * CDIM + quad * 8;
        f32x4 acc = {0.f, 0.f, 0.f, 0.f};
        #pragma unroll
        for (int ks = 0; ks < 8; ks++)
            acc = __builtin_amdgcn_mfma_f32_16x16x32_f16(*(const f16x8*)(wr + ks * 32), af[ks], acc, 0, 0, 0);
        const float4 bv = *(const float4*)(ob + ctg * 16 + quad * 4);
        const int c0 = ctg * 16 + quad * 4;
        float4 res;
        res.x = acc[0] + bv.x; res.y = acc[1] + bv.y;
        res.z = acc[2] + bv.z; res.w = acc[3] + bv.w;
        *(float4*)(out + (size_t)(row0 + l15) * CDIM + c0) = res;
    }
}

extern "C" void kernel_launch(void* const* d_in, const int* in_sizes, int n_in,
                              void* d_out, int out_size, void* d_ws, size_t ws_size,
                              hipStream_t stream) {
    const float* x   = (const float*)d_in[0];
    const float* qw  = (const float*)d_in[1];
    const float* qb  = (const float*)d_in[2];
    const float* kw  = (const float*)d_in[3];
    const float* kb  = (const float*)d_in[4];
    const float* vw  = (const float*)d_in[5];
    const float* vb  = (const float*)d_in[6];
    const float* ow  = (const float*)d_in[7];
    const float* ob  = (const float*)d_in[8];
    const float* tau = (const float*)d_in[9];

    // workspace layout:
    //   w16    : 4*65536 fp16              (512 KB)
    //   Q,K,Vt : 3*2097152 fp16            (12 MB)
    //   AO     : 2097152 fp16              (4 MB)
    //   Opart  : 4*2097152 fp32            (32 MB)
    //   lpart  : 4*8*4096 fp32             (512 KB)
    _Float16* w16 = (_Float16*)d_ws;
    _Float16* Q   = w16 + 262144;
    _Float16* K   = Q + 2097152;
    _Float16* Vt  = K + 2097152;
    _Float16* AO  = Vt + 2097152;
    float* Opart  = (float*)(AO + 2097152);
    float* lpart  = Opart + 8388608;

    sta_prep   <<<dim3(32, 4),      256, 0, stream>>>(qw, kw, vw, ow, w16);
    sta_qkv    <<<dim3(128, 3, 2),  256, 0, stream>>>(x, w16, qb, kb, vb, Q, K, Vt);
    sta_attn   <<<dim3(128, 8, 4),  128, 0, stream>>>(Q, K, Vt, tau, Opart, lpart);
    sta_combine<<<2048,             256, 0, stream>>>(Opart, lpart, AO);
    sta_oproj  <<<dim3(128, 4),     256, 0, stream>>>(AO, w16 + 3 * 65536, ob, (float*)d_out);
}

// Round 4
// 207.856 us; speedup vs baseline: 2.2571x; 1.8181x over previous
//
#include <hip/hip_runtime.h>

#define SEQ   4096
#define CDIM  256
#define NHEAD 4
#define DHEAD 64
#define PSTRIDE 72   // P-buffer row stride (f16): 144 B rows -> 16B-aligned b128 reads

typedef float    f32x4 __attribute__((ext_vector_type(4)));
typedef _Float16 f16x8 __attribute__((ext_vector_type(8)));
typedef _Float16 f16x4 __attribute__((ext_vector_type(4)));

__device__ __forceinline__ f16x8 cvt_frag(const float* __restrict__ p) {
    float4 f0 = *(const float4*)p;
    float4 f1 = *(const float4*)(p + 4);
    f16x8 r;
    r[0]=(_Float16)f0.x; r[1]=(_Float16)f0.y; r[2]=(_Float16)f0.z; r[3]=(_Float16)f0.w;
    r[4]=(_Float16)f1.x; r[5]=(_Float16)f1.y; r[6]=(_Float16)f1.z; r[7]=(_Float16)f1.w;
    return r;
}

// ---------------- Kernel 0: weight fp32->fp16 prep ----------------
__global__ __launch_bounds__(256) void sta_prep(
    const float* __restrict__ qw, const float* __restrict__ kw,
    const float* __restrict__ vw, const float* __restrict__ ow,
    _Float16* __restrict__ w16)
{
    const int mat = blockIdx.y;
    const float* src = (mat == 0) ? qw : (mat == 1) ? kw : (mat == 2) ? vw : ow;
    const int i = (blockIdx.x * 256 + threadIdx.x) * 8;
    *(f16x8*)(w16 + mat * 65536 + i) = cvt_frag(src + i);
}

// ---------------- Kernel 1: QKV projection ----------------
__global__ __launch_bounds__(256) void sta_qkv(
    const float* __restrict__ x, const _Float16* __restrict__ w16,
    const float* __restrict__ qb, const float* __restrict__ kb, const float* __restrict__ vb,
    _Float16* __restrict__ Qo, _Float16* __restrict__ Ko, _Float16* __restrict__ Vo)
{
    const int wave = threadIdx.x >> 6;
    const int lane = threadIdx.x & 63;
    const int l15  = lane & 15;
    const int quad = lane >> 4;
    const int mat  = blockIdx.y;
    const int half = blockIdx.z;
    const int row0 = blockIdx.x * 64 + wave * 16;

    const _Float16* w    = w16 + mat * 65536;
    const float*    bias = (mat == 0) ? qb : (mat == 1) ? kb : vb;

    f16x8 xf[8];
    const float* xrow = x + (row0 + l15) * CDIM + quad * 8;
    #pragma unroll
    for (int ks = 0; ks < 8; ks++) xf[ks] = cvt_frag(xrow + ks * 32);

    #pragma unroll 1
    for (int ct = 0; ct < 8; ct++) {
        const int ctg = half * 8 + ct;
        const _Float16* wr = w + (ctg * 16 + l15) * CDIM + quad * 8;
        f32x4 acc = {0.f, 0.f, 0.f, 0.f};
        if (mat < 2) {
            #pragma unroll
            for (int ks = 0; ks < 8; ks++)
                acc = __builtin_amdgcn_mfma_f32_16x16x32_f16(*(const f16x8*)(wr + ks * 32), xf[ks], acc, 0, 0, 0);
            const float4 bv = *(const float4*)(bias + ctg * 16 + quad * 4);
            const int c0 = ctg * 16 + quad * 4;
            const int h = c0 >> 6, d0 = c0 & 63;
            const int grow = row0 + l15, b = grow >> 12, n = grow & (SEQ - 1);
            const float sc = (mat == 0) ? 0.0625f : 1.0f;
            f16x4 o;
            o[0] = (_Float16)((acc[0] + bv.x) * sc);
            o[1] = (_Float16)((acc[1] + bv.y) * sc);
            o[2] = (_Float16)((acc[2] + bv.z) * sc);
            o[3] = (_Float16)((acc[3] + bv.w) * sc);
            _Float16* dst = ((mat == 0) ? Qo : Ko) + (((b * NHEAD + h) * SEQ + n) * DHEAD + d0);
            *(f16x4*)dst = o;
        } else {
            #pragma unroll
            for (int ks = 0; ks < 8; ks++)
                acc = __builtin_amdgcn_mfma_f32_16x16x32_f16(xf[ks], *(const f16x8*)(wr + ks * 32), acc, 0, 0, 0);
            const int c = ctg * 16 + l15;
            const int h = c >> 6, d = c & 63;
            const float bv = bias[c];
            const int grow0 = row0 + quad * 4, b = grow0 >> 12, n0 = grow0 & (SEQ - 1);
            f16x4 o;
            #pragma unroll
            for (int r = 0; r < 4; r++) o[r] = (_Float16)(acc[r] + bv);
            *(f16x4*)(Vo + (((b * NHEAD + h) * DHEAD + d) * SEQ + n0)) = o;
        }
    }
}

// ---------------- Kernel 2: flash attention, fat 1-wave blocks ----------------
// grid (64 q-tiles of 64, 8 bh, 4 kv-splits), 64 thr = 1 wave owning 64 Q-rows.
// QK^T computed operand-swapped: S[kv][q] -> lane's 4 C-regs are contiguous kv
// for one q => packed ds_write_b64 of P; PV reads P back as b128 A-fragments.
__global__ __launch_bounds__(64) void sta_attn(
    const _Float16* __restrict__ Q, const _Float16* __restrict__ K, const _Float16* __restrict__ Vt,
    const float* __restrict__ taup,
    float* __restrict__ Opart, float* __restrict__ lpart)
{
    __shared__ __align__(16) _Float16 pbuf[64 * PSTRIDE];   // wave-private, no barriers

    const int lane = threadIdx.x;
    const int l15  = lane & 15;
    const int quad = lane >> 4;
    const int qt = blockIdx.x;   // 0..63
    const int bh = blockIdx.y;   // 0..7
    const int sp = blockIdx.z;   // 0..3
    const float tau_eff = fmaxf(taup[0], 0.0f);

    const _Float16* Qb = Q  + bh * SEQ * DHEAD;
    const _Float16* Kb = K  + bh * SEQ * DHEAD;
    const _Float16* Vb = Vt + bh * DHEAD * SEQ;

    const int q0 = qt * 64;

    // Q B-fragments, held for the whole sweep: col=l15 -> q, k=quad*8+j -> d
    f16x8 qf[4][2];
    #pragma unroll
    for (int qb = 0; qb < 4; qb++)
        #pragma unroll
        for (int ks = 0; ks < 2; ks++)
            qf[qb][ks] = *(const f16x8*)(Qb + (q0 + qb * 16 + l15) * DHEAD + ks * 32 + quad * 8);

    f32x4 O[4][4];   // [qb][db]
    #pragma unroll
    for (int qb = 0; qb < 4; qb++)
        #pragma unroll
        for (int db = 0; db < 4; db++) O[qb][db] = (f32x4){0.f, 0.f, 0.f, 0.f};
    float rs[4] = {0.f, 0.f, 0.f, 0.f};   // per-lane denominator partials, q = q0+qb*16+l15

    #pragma unroll 1
    for (int kt = sp * 16; kt < sp * 16 + 16; kt++) {
        const int kv0 = kt * 64;

        // ---- S' = K Q^T (swapped): rows=kv, cols=q. Gate+exp, packed b64 P-writes.
        #pragma unroll
        for (int kb = 0; kb < 4; kb++) {
            const _Float16* kp = Kb + (kv0 + kb * 16 + l15) * DHEAD + quad * 8;
            f16x8 k0 = *(const f16x8*)kp;
            f16x8 k1 = *(const f16x8*)(kp + 32);
            #pragma unroll
            for (int qb = 0; qb < 4; qb++) {
                f32x4 a = {0.f, 0.f, 0.f, 0.f};
                a = __builtin_amdgcn_mfma_f32_16x16x32_f16(k0, qf[qb][0], a, 0, 0, 0);
                a = __builtin_amdgcn_mfma_f32_16x16x32_f16(k1, qf[qb][1], a, 0, 0, 0);
                // lane holds S[kv0+kb*16+quad*4+r][q0+qb*16+l15], r=0..3
                f16x4 pk;
                float acc = 0.f;
                #pragma unroll
                for (int r = 0; r < 4; r++) {
                    float e = __expf(a[r]);
                    float p = (a[r] > tau_eff) ? e : 1.0f;   // gate-off -> exp(0)=1
                    acc += p;
                    pk[r] = (_Float16)p;
                }
                rs[qb] += acc;
                // P row-major [q_local][kv_local], 4 contiguous kv per lane
                *(f16x4*)(pbuf + (qb * 16 + l15) * PSTRIDE + kb * 16 + quad * 4) = pk;
            }
        }

        // ---- O += P V: A=P (b128 reads), B=Vt (contiguous). Same-wave LDS, no barrier.
        #pragma unroll
        for (int ks = 0; ks < 2; ks++) {
            f16x8 pa[4];
            #pragma unroll
            for (int qb = 0; qb < 4; qb++)
                pa[qb] = *(const f16x8*)(pbuf + (qb * 16 + l15) * PSTRIDE + ks * 32 + quad * 8);
            #pragma unroll
            for (int db = 0; db < 4; db++) {
                f16x8 vf = *(const f16x8*)(Vb + (db * 16 + l15) * SEQ + kv0 + ks * 32 + quad * 8);
                #pragma unroll
                for (int qb = 0; qb < 4; qb++)
                    O[qb][db] = __builtin_amdgcn_mfma_f32_16x16x32_f16(pa[qb], vf, O[qb][db], 0, 0, 0);
            }
        }
    }

    // ---- epilogue: finish denominators (sum over kv-quads), store fp32 partials ----
    #pragma unroll
    for (int qb = 0; qb < 4; qb++) {
        float v = rs[qb];
        v += __shfl_xor(v, 16);
        v += __shfl_xor(v, 32);
        rs[qb] = v;
    }
    float* Ob = Opart + (size_t)((sp * 8 + bh) * SEQ + q0) * DHEAD;
    #pragma unroll
    for (int qb = 0; qb < 4; qb++)
        #pragma unroll
        for (int db = 0; db < 4; db++)
            #pragma unroll
            for (int r = 0; r < 4; r++)
                Ob[(qb * 16 + quad * 4 + r) * DHEAD + db * 16 + l15] = O[qb][db][r];
    if (quad == 0) {
        #pragma unroll
        for (int qb = 0; qb < 4; qb++)
            lpart[(sp * 8 + bh) * SEQ + q0 + qb * 16 + l15] = rs[qb];
    }
}

// ---------------- Kernel 3: combine split-KV partials ----------------
__global__ __launch_bounds__(256) void sta_combine(
    const float* __restrict__ Opart, const float* __restrict__ lpart,
    _Float16* __restrict__ AO)
{
    const int idx = blockIdx.x * 256 + threadIdx.x;     // 524288
    const int dg = idx & 15, n = (idx >> 4) & (SEQ - 1), bh = idx >> 16;
    const int d0 = dg * 4;
    float4 o = {0.f, 0.f, 0.f, 0.f};
    float l = 0.f;
    #pragma unroll
    for (int s = 0; s < 4; s++) {
        const float4 os = *(const float4*)(Opart + (size_t)((s * 8 + bh) * SEQ + n) * DHEAD + d0);
        o.x += os.x; o.y += os.y; o.z += os.z; o.w += os.w;
        l += lpart[(s * 8 + bh) * SEQ + n];
    }
    const float inv = 1.0f / l;
    const int b = bh >> 2, h = bh & 3;
    f16x4 res;
    res[0] = (_Float16)(o.x * inv); res[1] = (_Float16)(o.y * inv);
    res[2] = (_Float16)(o.z * inv); res[3] = (_Float16)(o.w * inv);
    *(f16x4*)(AO + (size_t)(b * SEQ + n) * CDIM + h * DHEAD + d0) = res;
}

// ---------------- Kernel 4: output projection ----------------
__global__ __launch_bounds__(256) void sta_oproj(
    const _Float16* __restrict__ AO, const _Float16* __restrict__ w16o,
    const float* __restrict__ ob, float* __restrict__ out)
{
    const int wave = threadIdx.x >> 6;
    const int lane = threadIdx.x & 63;
    const int l15  = lane & 15;
    const int quad = lane >> 4;
    const int row0 = blockIdx.x * 64 + wave * 16;
    const int quarter = blockIdx.y;

    f16x8 af[8];
    const _Float16* arow = AO + (row0 + l15) * CDIM + quad * 8;
    #pragma unroll
    for (int ks = 0; ks < 8; ks++) af[ks] = *(const f16x8*)(arow + ks * 32);

    #pragma unroll 1
    for (int ct = 0; ct < 4; ct++) {
        const int ctg = quarter * 4 + ct;
        const _Float16* wr = w16o + (ctg * 16 + l15) * CDIM + quad * 8;
        f32x4 acc = {0.f, 0.f, 0.f, 0.f};
        #pragma unroll
        for (int ks = 0; ks < 8; ks++)
            acc = __builtin_amdgcn_mfma_f32_16x16x32_f16(*(const f16x8*)(wr + ks * 32), af[ks], acc, 0, 0, 0);
        const float4 bv = *(const float4*)(ob + ctg * 16 + quad * 4);
        const int c0 = ctg * 16 + quad * 4;
        float4 res;
        res.x = acc[0] + bv.x; res.y = acc[1] + bv.y;
        res.z = acc[2] + bv.z; res.w = acc[3] + bv.w;
        *(float4*)(out + (size_t)(row0 + l15) * CDIM + c0) = res;
    }
}

extern "C" void kernel_launch(void* const* d_in, const int* in_sizes, int n_in,
                              void* d_out, int out_size, void* d_ws, size_t ws_size,
                              hipStream_t stream) {
    const float* x   = (const float*)d_in[0];
    const float* qw  = (const float*)d_in[1];
    const float* qb  = (const float*)d_in[2];
    const float* kw  = (const float*)d_in[3];
    const float* kb  = (const float*)d_in[4];
    const float* vw  = (const float*)d_in[5];
    const float* vb  = (const float*)d_in[6];
    const float* ow  = (const float*)d_in[7];
    const float* ob  = (const float*)d_in[8];
    const float* tau = (const float*)d_in[9];

    _Float16* w16 = (_Float16*)d_ws;
    _Float16* Q   = w16 + 262144;
    _Float16* K   = Q + 2097152;
    _Float16* Vt  = K + 2097152;
    _Float16* AO  = Vt + 2097152;
    float* Opart  = (float*)(AO + 2097152);
    float* lpart  = Opart + 8388608;

    sta_prep   <<<dim3(32, 4),      256, 0, stream>>>(qw, kw, vw, ow, w16);
    sta_qkv    <<<dim3(128, 3, 2),  256, 0, stream>>>(x, w16, qb, kb, vb, Q, K, Vt);
    sta_attn   <<<dim3(64, 8, 4),    64, 0, stream>>>(Q, K, Vt, tau, Opart, lpart);
    sta_combine<<<2048,             256, 0, stream>>>(Opart, lpart, AO);
    sta_oproj  <<<dim3(128, 4),     256, 0, stream>>>(AO, ow ? (w16 + 3 * 65536) : (w16 + 3 * 65536), ob, (float*)d_out);
}